// Round 4
// baseline (2920.260 us; speedup 1.0000x reference)
//
#include <hip/hip_runtime.h>
#include <stdint.h>

constexpr int NB = 32, NS = 64, NT = 64, NV = 32000, NE = 256, NH = 512;
constexpr int TSTEPS = NS + NT - 1;   // 127

typedef unsigned short u16;
typedef short bf16x8 __attribute__((ext_vector_type(8)));
typedef float f32x4  __attribute__((ext_vector_type(4)));

__device__ inline u16 f2bf(float f){
  unsigned int u = __float_as_uint(f);
  u = u + 0x7FFFu + ((u >> 16) & 1u);
  return (u16)(u >> 16);
}

__device__ inline void gload_lds16(const u16* g, u16* l){
  __builtin_amdgcn_global_load_lds((const __attribute__((address_space(1))) void*)g,
                                   (__attribute__((address_space(3))) void*)l, 16, 0, 0);
}

// ---------------------------------------------------------------- zero init (out row 0, pad rows)
__global__ void zero_init(float* __restrict__ out, u16* __restrict__ xdecpad, u16* __restrict__ hallpad){
  int i = blockIdx.x * blockDim.x + threadIdx.x, st = gridDim.x * blockDim.x;
  for (int idx = i; idx < NB * NV; idx += st){
    int b = idx / NV, v = idx - b * NV;
    out[(size_t)b * NT * NV + v] = 0.f;
  }
  for (int idx = i; idx < 32 * NE; idx += st) xdecpad[idx] = 0;
  for (int idx = i; idx < 32 * NH; idx += st) hallpad[idx] = 0;
}

// ---------------------------------------------------------------- f32 -> bf16
__global__ void cvt_f32_bf16(const float* __restrict__ in, u16* __restrict__ out, int n4){
  int i = blockIdx.x * blockDim.x + threadIdx.x, st = gridDim.x * blockDim.x;
  for (int idx = i; idx < n4; idx += st){
    float4 v = ((const float4*)in)[idx];
    unsigned lo = (unsigned)f2bf(v.x) | ((unsigned)f2bf(v.y) << 16);
    unsigned hi = (unsigned)f2bf(v.z) | ((unsigned)f2bf(v.w) << 16);
    *(uint2*)(out + (size_t)idx * 4) = make_uint2(lo, hi);
  }
}

// ---------------------------------------------------------------- W_hh (1536x512) -> Wq[k4][g] float4 pack
// Wq element (k4, g) = { W[g][4*k4+0..3] }.  Tiled 64x64 transpose via LDS.
__global__ __launch_bounds__(256) void wpack(const float* __restrict__ W, float* __restrict__ Wq){
  __shared__ float tile[64][65];
  const int g0 = blockIdx.x * 64;     // 24 tiles over 1536
  const int k0 = blockIdx.y * 64;     // 8 tiles over 512
  const int t = threadIdx.x;
  {
    const int ir = t >> 4, jc = t & 15;
    #pragma unroll
    for (int rr = 0; rr < 4; ++rr){
      int row = rr * 16 + ir;
      f32x4 v = *(const f32x4*)(W + (size_t)(g0 + row) * NH + k0 + jc * 4);
      tile[row][jc*4+0] = v[0]; tile[row][jc*4+1] = v[1];
      tile[row][jc*4+2] = v[2]; tile[row][jc*4+3] = v[3];
    }
  }
  __syncthreads();
  {
    const int k4l = t >> 6, gl = t & 63;
    #pragma unroll
    for (int ss = 0; ss < 4; ++ss){
      int k4 = (k0 >> 2) + ss * 4 + k4l;
      int cl = (ss * 4 + k4l) * 4;
      f32x4 v = { tile[gl][cl+0], tile[gl][cl+1], tile[gl][cl+2], tile[gl][cl+3] };
      *(f32x4*)(Wq + ((size_t)k4 * 1536 + g0 + gl) * 4) = v;
    }
  }
}

// ---------------------------------------------------------------- embedding gather (rows m = t*NB + b)
__global__ void embed_k(const int* __restrict__ idx, int ld, int tcount,
                        const float* __restrict__ emb, u16* __restrict__ xbf){
  int tid = blockIdx.x * blockDim.x + threadIdx.x;
  int n4 = tcount * NB * (NE / 4);
  if (tid >= n4) return;
  int e4 = tid & (NE/4 - 1);
  int m  = tid >> 6;
  int t = m / NB, b = m % NB;
  int row = idx[b * ld + t];
  float4 v = ((const float4*)(emb + (size_t)row * NE))[e4];
  unsigned lo = (unsigned)f2bf(v.x) | ((unsigned)f2bf(v.y) << 16);
  unsigned hi = (unsigned)f2bf(v.z) | ((unsigned)f2bf(v.w) << 16);
  *(uint2*)(xbf + (size_t)m * NE + e4 * 4) = make_uint2(lo, hi);
}

// ---------------------------------------------------------------- bf16 MFMA GEMM: C = A(MxK) * B(NxK)^T + bias
template<int KDIM, bool SCATTER>
__global__ __launch_bounds__(256) void gemm_bt(const u16* __restrict__ A,
                                               const u16* __restrict__ Bm,
                                               const float* __restrict__ bias,
                                               float* __restrict__ C,
                                               int Mstore, int Nld)
{
  __shared__ u16 As[128 * 32];
  __shared__ u16 Bs[128 * 32];
  const int id = blockIdx.x;
  const int q = gridDim.x >> 3;
  const int wg = (id & 7) * q + (id >> 3);
  const int m0 = (wg & 15) * 128, n0 = (wg >> 4) * 128;
  const int tid  = threadIdx.x;
  const int lane = tid & 63;
  const int w = tid >> 6, wm = w >> 1, wn = w & 1;
  f32x4 acc[4][4] = {};

  const int sr = w * 16 + (lane >> 2);
  const int sc = (lane & 3) * 8;
  const u16* aS = A  + (size_t)(m0 + sr) * KDIM + sc;
  const u16* bS = Bm + (size_t)(n0 + sr) * KDIM + sc;
  u16* asl = As + w * 16 * 32;
  u16* bsl = Bs + w * 16 * 32;

  for (int k0 = 0; k0 < KDIM; k0 += 32){
    gload_lds16(aS + k0, asl);
    gload_lds16(aS + (size_t)64 * KDIM + k0, asl + 64 * 32);
    gload_lds16(bS + k0, bsl);
    gload_lds16(bS + (size_t)64 * KDIM + k0, bsl + 64 * 32);
    __syncthreads();
    bf16x8 af[4], bfr[4];
    #pragma unroll
    for (int i = 0; i < 4; ++i)
      af[i] = *(const bf16x8*)((const char*)As + (wm*64 + i*16 + (lane & 15)) * 64 + (lane >> 4) * 16);
    #pragma unroll
    for (int j = 0; j < 4; ++j)
      bfr[j] = *(const bf16x8*)((const char*)Bs + (wn*64 + j*16 + (lane & 15)) * 64 + (lane >> 4) * 16);
    #pragma unroll
    for (int i = 0; i < 4; ++i)
      #pragma unroll
      for (int j = 0; j < 4; ++j)
        acc[i][j] = __builtin_amdgcn_mfma_f32_16x16x32_bf16(af[i], bfr[j], acc[i][j], 0, 0, 0);
    __syncthreads();
  }

  #pragma unroll
  for (int i = 0; i < 4; ++i){
    #pragma unroll
    for (int j = 0; j < 4; ++j){
      int col = n0 + wn*64 + j*16 + (lane & 15);
      float bv = bias[col];
      #pragma unroll
      for (int rr = 0; rr < 4; ++rr){
        int row = m0 + wm*64 + i*16 + (lane >> 4) * 4 + rr;
        float val = acc[i][j][rr] + bv;
        if (SCATTER){
          if (row < Mstore){
            int t = row >> 5, b = row & 31;
            C[(size_t)b * (NT * NV) + (size_t)(t + 1) * NV + col] = val;
          }
        } else {
          C[(size_t)row * Nld + col] = val;
        }
      }
    }
  }
}

// ---------------------------------------------------------------- batch-split GRU recurrence (fp32, no grid sync)
// 32 wgs (one per batch element) x 512 threads (one per hidden unit).
// h lives in LDS for all 127 steps. Thread j computes all 3 gate dots for unit j
// (no reduction). W streamed from Wq[k4][g] float4 layout -> coalesced, L2-resident.
__global__ __launch_bounds__(512) void gru_batch(
    const f32x4* __restrict__ WqE, const f32x4* __restrict__ WqD,
    const float* __restrict__ bhhE, const float* __restrict__ bhhD,
    const float* __restrict__ gie, const float* __restrict__ gid,
    u16* __restrict__ Hall)
{
  __shared__ float hs[NH];
  const int j = threadIdx.x;
  const int b = blockIdx.x;
  hs[j] = 0.f;
  const float beR = bhhE[j], beZ = bhhE[NH + j], beN = bhhE[2*NH + j];
  const float bdR = bhhD[j], bdZ = bhhD[NH + j], bdN = bhhD[2*NH + j];
  __syncthreads();

  for (int t = 0; t < TSTEPS; ++t){
    const bool dec = (t >= NS);
    const float* gi = dec ? (gid + ((size_t)(t - NS) * NB + b) * 3 * NH)
                          : (gie + ((size_t)t * NB + b) * 3 * NH);
    float gr = gi[j], gz = gi[NH + j], gn = gi[2*NH + j];   // issue early, hide under loop
    const f32x4* wp = (dec ? WqD : WqE) + j;
    const f32x4* h4 = (const f32x4*)hs;
    f32x4 a0 = {0,0,0,0}, a1 = {0,0,0,0}, a2 = {0,0,0,0};
    #pragma unroll 4
    for (int k4 = 0; k4 < NH/4; ++k4){
      f32x4 hv = h4[k4];          // LDS broadcast (all lanes same addr)
      a0 += wp[0]    * hv;
      a1 += wp[512]  * hv;
      a2 += wp[1024] * hv;
      wp += 1536;
    }
    float sr = a0[0]+a0[1]+a0[2]+a0[3];
    float sz = a1[0]+a1[1]+a1[2]+a1[3];
    float sn = a2[0]+a2[1]+a2[2]+a2[3];
    float br = dec ? bdR : beR, bz = dec ? bdZ : beZ, bn = dec ? bdN : beN;
    float r = 1.f / (1.f + expf(-(gr + sr + br)));
    float z = 1.f / (1.f + expf(-(gz + sz + bz)));
    float n = tanhf(gn + r * (sn + bn));
    float hold = hs[j];
    float hnew = (1.f - z) * n + z * hold;
    __syncthreads();                          // all reads of h(t) done
    hs[j] = hnew;
    if (dec) Hall[((size_t)(t - NS) * NB + b) * NH + j] = f2bf(hnew);
    __syncthreads();                          // h(t+1) visible
  }
}

// ---------------------------------------------------------------- launcher
extern "C" void kernel_launch(void* const* d_in, const int* in_sizes, int n_in,
                              void* d_out, int out_size, void* d_ws, size_t ws_size,
                              hipStream_t stream)
{
  const int*   src      = (const int*)  d_in[0];
  const int*   trg      = (const int*)  d_in[1];
  const float* emb_enc  = (const float*)d_in[2];
  const float* W_ih_enc = (const float*)d_in[3];
  const float* W_hh_enc = (const float*)d_in[4];
  const float* b_ih_enc = (const float*)d_in[5];
  const float* b_hh_enc = (const float*)d_in[6];
  const float* emb_dec  = (const float*)d_in[7];
  const float* W_ih_dec = (const float*)d_in[8];
  const float* W_hh_dec = (const float*)d_in[9];
  const float* b_ih_dec = (const float*)d_in[10];
  const float* b_hh_dec = (const float*)d_in[11];
  const float* fc_W     = (const float*)d_in[12];
  const float* fc_b     = (const float*)d_in[13];
  float* out = (float*)d_out;

  char* ws = (char*)d_ws;
  size_t o = 0;
  auto alloc = [&](size_t bytes){ size_t r = o; o += (bytes + 255) & ~(size_t)255; return r; };
  u16*   xenc  = (u16*)(ws + alloc((size_t)2048 * NE * 2));
  u16*   xdec  = (u16*)(ws + alloc((size_t)2048 * NE * 2));   // 2016 used + 32 pad
  u16*   wihe  = (u16*)(ws + alloc((size_t)3 * NH * NE * 2));
  u16*   wihd  = (u16*)(ws + alloc((size_t)3 * NH * NE * 2));
  u16*   fcWbf = (u16*)(ws + alloc((size_t)NV * NH * 2));
  float* WqE   = (float*)(ws + alloc((size_t)3 * NH * NH * 4));  // 3 MB packed W^T enc
  float* WqD   = (float*)(ws + alloc((size_t)3 * NH * NH * 4));  // 3 MB packed W^T dec
  float* gie   = (float*)(ws + alloc((size_t)2048 * 3 * NH * 4));
  float* gid   = (float*)(ws + alloc((size_t)2048 * 3 * NH * 4));
  u16*   Hall  = (u16*)(ws + alloc((size_t)2048 * NH * 2));   // 2016 used + 32 pad

  zero_init<<<256, 256, 0, stream>>>(out, xdec + (size_t)2016 * NE, Hall + (size_t)2016 * NH);
  cvt_f32_bf16<<<384, 256, 0, stream>>>(W_ih_enc, wihe, 3*NH*NE/4);
  cvt_f32_bf16<<<384, 256, 0, stream>>>(W_ih_dec, wihd, 3*NH*NE/4);
  cvt_f32_bf16<<<2048, 256, 0, stream>>>(fc_W, fcWbf, NV*NH/4);
  wpack<<<dim3(24, 8), 256, 0, stream>>>(W_hh_enc, WqE);
  wpack<<<dim3(24, 8), 256, 0, stream>>>(W_hh_dec, WqD);
  embed_k<<<(NS*NB*64 + 255)/256, 256, 0, stream>>>(src, NS, NS, emb_enc, xenc);
  embed_k<<<((NT-1)*NB*64 + 255)/256, 256, 0, stream>>>(trg, NT, NT-1, emb_dec, xdec);

  // gi = x @ W_ih^T + b_ih   (M=2048, N=1536, K=256) -> grid 12*16 = 192
  gemm_bt<NE, false><<<192, 256, 0, stream>>>(xenc, wihe, b_ih_enc, gie, 2048, 3*NH);
  gemm_bt<NE, false><<<192, 256, 0, stream>>>(xdec, wihd, b_ih_dec, gid, 2048, 3*NH);

  // batch-split recurrence: 32 independent wgs, no grid sync
  gru_batch<<<NB, 512, 0, stream>>>((const f32x4*)WqE, (const f32x4*)WqD,
                                    b_hh_enc, b_hh_dec, gie, gid, Hall);

  // logits = h2 @ fc_W^T + fc_b  (M=2048 pad, N=32000, K=512) -> grid 250*16 = 4000
  gemm_bt<NH, true><<<4000, 256, 0, stream>>>(Hall, fcWbf, fc_b, out, 2016, 0);
}

// Round 5
// 973.778 us; speedup vs baseline: 2.9989x; 2.9989x over previous
//
#include <hip/hip_runtime.h>
#include <stdint.h>

constexpr int NB = 32, NS = 64, NT = 64, NV = 32000, NE = 256, NH = 512;
constexpr int RG = 64;          // recurrence workgroups
constexpr int HU = 8;           // hidden units per wg
constexpr int GR = 3 * HU;      // 24 gate rows per wg
constexpr int TSTEPS = NS + NT - 1;   // 127

typedef unsigned short u16;
typedef unsigned long long u64;
typedef short bf16x8 __attribute__((ext_vector_type(8)));
typedef float f32x4  __attribute__((ext_vector_type(4)));

__device__ inline u16 f2bf(float f){
  unsigned int u = __float_as_uint(f);
  u = u + 0x7FFFu + ((u >> 16) & 1u);
  return (u16)(u >> 16);
}
__device__ inline float bf2f(u16 h){ return __uint_as_float(((unsigned)h) << 16); }

__device__ inline void gload_lds16(const u16* g, u16* l){
  __builtin_amdgcn_global_load_lds((const __attribute__((address_space(1))) void*)g,
                                   (__attribute__((address_space(3))) void*)l, 16, 0, 0);
}

// ---------------------------------------------------------------- zero init (out row 0, pads, h slot, flags)
__global__ void zero_init(float* __restrict__ out, u16* __restrict__ xdecpad, u16* __restrict__ hallpad,
                          unsigned* __restrict__ Hpk, unsigned* __restrict__ flags){
  int i = blockIdx.x * blockDim.x + threadIdx.x, st = gridDim.x * blockDim.x;
  for (int idx = i; idx < NB * NV; idx += st){
    int b = idx / NV, v = idx - b * NV;
    out[(size_t)b * NT * NV + v] = 0.f;
  }
  for (int idx = i; idx < 32 * NE; idx += st) xdecpad[idx] = 0;
  for (int idx = i; idx < 32 * NH; idx += st) hallpad[idx] = 0;
  for (int idx = i; idx < 2 * NB * NH; idx += st) Hpk[idx] = 0;   // h slots (slot0 = h(0) = 0)
  for (int idx = i; idx < 1024; idx += st) flags[idx] = 0;        // step flags
}

// ---------------------------------------------------------------- f32 -> bf16
__global__ void cvt_f32_bf16(const float* __restrict__ in, u16* __restrict__ out, int n4){
  int i = blockIdx.x * blockDim.x + threadIdx.x, st = gridDim.x * blockDim.x;
  for (int idx = i; idx < n4; idx += st){
    float4 v = ((const float4*)in)[idx];
    unsigned lo = (unsigned)f2bf(v.x) | ((unsigned)f2bf(v.y) << 16);
    unsigned hi = (unsigned)f2bf(v.z) | ((unsigned)f2bf(v.w) << 16);
    *(uint2*)(out + (size_t)idx * 4) = make_uint2(lo, hi);
  }
}

// ---------------------------------------------------------------- f32 -> (bf16 hi, bf16 lo)
__global__ void cvt_hilo(const float* __restrict__ in, u16* __restrict__ hi, u16* __restrict__ lo, int n){
  int i = blockIdx.x * blockDim.x + threadIdx.x, st = gridDim.x * blockDim.x;
  for (int idx = i; idx < n; idx += st){
    float w = in[idx];
    u16 h = f2bf(w);
    hi[idx] = h;
    lo[idx] = f2bf(w - bf2f(h));
  }
}

// ---------------------------------------------------------------- embedding gather (rows m = t*NB + b)
__global__ void embed_k(const int* __restrict__ idx, int ld, int tcount,
                        const float* __restrict__ emb, u16* __restrict__ xbf){
  int tid = blockIdx.x * blockDim.x + threadIdx.x;
  int n4 = tcount * NB * (NE / 4);
  if (tid >= n4) return;
  int e4 = tid & (NE/4 - 1);
  int m  = tid >> 6;
  int t = m / NB, b = m % NB;
  int row = idx[b * ld + t];
  float4 v = ((const float4*)(emb + (size_t)row * NE))[e4];
  unsigned lo = (unsigned)f2bf(v.x) | ((unsigned)f2bf(v.y) << 16);
  unsigned hi = (unsigned)f2bf(v.z) | ((unsigned)f2bf(v.w) << 16);
  *(uint2*)(xbf + (size_t)m * NE + e4 * 4) = make_uint2(lo, hi);
}

// ---------------------------------------------------------------- bf16 MFMA GEMM: C = A(MxK) * B(NxK)^T + bias
template<int KDIM, bool SCATTER>
__global__ __launch_bounds__(256) void gemm_bt(const u16* __restrict__ A,
                                               const u16* __restrict__ Bm,
                                               const float* __restrict__ bias,
                                               float* __restrict__ C,
                                               int Mstore, int Nld)
{
  __shared__ u16 As[128 * 32];
  __shared__ u16 Bs[128 * 32];
  const int id = blockIdx.x;
  const int q = gridDim.x >> 3;
  const int wg = (id & 7) * q + (id >> 3);
  const int m0 = (wg & 15) * 128, n0 = (wg >> 4) * 128;
  const int tid  = threadIdx.x;
  const int lane = tid & 63;
  const int w = tid >> 6, wm = w >> 1, wn = w & 1;
  f32x4 acc[4][4] = {};

  const int sr = w * 16 + (lane >> 2);
  const int sc = (lane & 3) * 8;
  const u16* aS = A  + (size_t)(m0 + sr) * KDIM + sc;
  const u16* bS = Bm + (size_t)(n0 + sr) * KDIM + sc;
  u16* asl = As + w * 16 * 32;
  u16* bsl = Bs + w * 16 * 32;

  for (int k0 = 0; k0 < KDIM; k0 += 32){
    gload_lds16(aS + k0, asl);
    gload_lds16(aS + (size_t)64 * KDIM + k0, asl + 64 * 32);
    gload_lds16(bS + k0, bsl);
    gload_lds16(bS + (size_t)64 * KDIM + k0, bsl + 64 * 32);
    __syncthreads();
    bf16x8 af[4], bfr[4];
    #pragma unroll
    for (int i = 0; i < 4; ++i)
      af[i] = *(const bf16x8*)((const char*)As + (wm*64 + i*16 + (lane & 15)) * 64 + (lane >> 4) * 16);
    #pragma unroll
    for (int j = 0; j < 4; ++j)
      bfr[j] = *(const bf16x8*)((const char*)Bs + (wn*64 + j*16 + (lane & 15)) * 64 + (lane >> 4) * 16);
    #pragma unroll
    for (int i = 0; i < 4; ++i)
      #pragma unroll
      for (int j = 0; j < 4; ++j)
        acc[i][j] = __builtin_amdgcn_mfma_f32_16x16x32_bf16(af[i], bfr[j], acc[i][j], 0, 0, 0);
    __syncthreads();
  }

  #pragma unroll
  for (int i = 0; i < 4; ++i){
    #pragma unroll
    for (int j = 0; j < 4; ++j){
      int col = n0 + wn*64 + j*16 + (lane & 15);
      float bv = bias[col];
      #pragma unroll
      for (int rr = 0; rr < 4; ++rr){
        int row = m0 + wm*64 + i*16 + (lane >> 4) * 4 + rr;
        float val = acc[i][j][rr] + bv;
        if (SCATTER){
          if (row < Mstore){
            int t = row >> 5, b = row & 31;
            C[(size_t)b * (NT * NV) + (size_t)(t + 1) * NV + col] = val;
          }
        } else {
          C[(size_t)row * Nld + col] = val;
        }
      }
    }
  }
}

// ---------------------------------------------------------------- persistent GRU recurrence (MALL-coherent sync)
// 64 wgs x 256 thr; wg owns 8 hidden units (24 gate rows) of W_hh in LDS (bf16 hi+lo).
// h exchanged via relaxed AGENT-scope atomics (bypass L1/L2 -> MALL). No fences:
// __syncthreads drains vmcnt (stores acked at MALL) before the per-wg flag store.
// Barrier = 64 independent flag stores + 64-lane parallel poll (no RMW serialization).
// h slots double-buffered by step parity; flags monotone (poll uses >=).
__global__ __launch_bounds__(256) void gru_rec(
    const u16* __restrict__ WhiE, const u16* __restrict__ WloE,
    const u16* __restrict__ WhiD, const u16* __restrict__ WloD,
    const float* __restrict__ bhhE, const float* __restrict__ bhhD,
    const float* __restrict__ gie, const float* __restrict__ gid,
    unsigned* __restrict__ Hpk,     // [2][NB][NH] u32 = (hi | lo<<16)
    unsigned* __restrict__ flags,   // [64] strided by 4 u32 (16B)
    u16* __restrict__ Hall)
{
  extern __shared__ char smem[];
  u16* Whi = (u16*)smem;              // [24][512] swizzled
  u16* Wlo = Whi + GR * NH;
  u16* Hhi = Wlo + GR * NH;           // [32][512] swizzled
  u16* Hlo = Hhi + NB * NH;
  float* GH = (float*)(Hlo + NB * NH);// [24][32]

  const int tid  = threadIdx.x;
  const int lane = tid & 63;
  const int w    = tid >> 6;          // 0..3
  const int mt   = w >> 1, nt = w & 1;
  const int j0   = blockIdx.x * HU;

  // hoisted per-thread constants for the gate phase
  const int gjj = tid >> 5, gb = tid & 31;
  const int jg  = j0 + gjj;
  const float beR = bhhE[jg], beZ = bhhE[NH + jg], beN = bhhE[2*NH + jg];
  const float bdR = bhhD[jg], bdZ = bhhD[NH + jg], bdN = bhhD[2*NH + jg];

  // ---- stage encoder W slice (hi/lo)
  for (int c = tid; c < GR * 64; c += 256){
    int r = c >> 6, c16 = c & 63;
    int grow = (r >> 3) * NH + j0 + (r & 7);
    int d = (r << 10) | ((c16 * 16) ^ ((r & 7) << 4));
    *(uint4*)((char*)Whi + d) = *(const uint4*)(WhiE + (size_t)grow * NH + c16 * 8);
    *(uint4*)((char*)Wlo + d) = *(const uint4*)(WloE + (size_t)grow * NH + c16 * 8);
  }
  __syncthreads();

  for (int t = 0; t < TSTEPS; ++t){
    const bool dec = (t >= NS);
    if (t == NS){
      for (int c = tid; c < GR * 64; c += 256){
        int r = c >> 6, c16 = c & 63;
        int grow = (r >> 3) * NH + j0 + (r & 7);
        int d = (r << 10) | ((c16 * 16) ^ ((r & 7) << 4));
        *(uint4*)((char*)Whi + d) = *(const uint4*)(WhiD + (size_t)grow * NH + c16 * 8);
        *(uint4*)((char*)Wlo + d) = *(const uint4*)(WloD + (size_t)grow * NH + c16 * 8);
      }
      __syncthreads();
    }

    // ---- wait: all 64 wgs published h(t)  (wave 0 polls, lane l watches flag[l])
    if (w == 0){
      int spins = 0;
      while (true){
        unsigned f = __hip_atomic_load(&flags[lane * 4], __ATOMIC_RELAXED, __HIP_MEMORY_SCOPE_AGENT);
        if (__all((int)(f >= (unsigned)t))) break;
        __builtin_amdgcn_s_sleep(2);
        if (++spins > (1 << 20)) break;   // failsafe: deadlock -> wrong answer, not hang
      }
    }
    __syncthreads();

    // ---- stage h(t) from Hpk[t&1] (MALL) into swizzled LDS hi/lo planes
    {
      const u64* Hq = (const u64*)(Hpk + (size_t)(t & 1) * NB * NH);
      #pragma unroll
      for (int i = 0; i < 8; ++i){
        int c = tid + 256 * i;          // chunk = 8 consecutive k of one row b
        int b = c >> 6, kc = c & 63;
        const u64* p = Hq + (size_t)b * (NH / 2) + kc * 4;
        u64 q0 = __hip_atomic_load(p + 0, __ATOMIC_RELAXED, __HIP_MEMORY_SCOPE_AGENT);
        u64 q1 = __hip_atomic_load(p + 1, __ATOMIC_RELAXED, __HIP_MEMORY_SCOPE_AGENT);
        u64 q2 = __hip_atomic_load(p + 2, __ATOMIC_RELAXED, __HIP_MEMORY_SCOPE_AGENT);
        u64 q3 = __hip_atomic_load(p + 3, __ATOMIC_RELAXED, __HIP_MEMORY_SCOPE_AGENT);
        unsigned a0 = (unsigned)q0, a1 = (unsigned)(q0 >> 32);
        unsigned b0 = (unsigned)q1, b1 = (unsigned)(q1 >> 32);
        unsigned c0 = (unsigned)q2, c1 = (unsigned)(q2 >> 32);
        unsigned d0 = (unsigned)q3, d1 = (unsigned)(q3 >> 32);
        uint4 hw = make_uint4((a0 & 0xffffu) | (a1 << 16), (b0 & 0xffffu) | (b1 << 16),
                              (c0 & 0xffffu) | (c1 << 16), (d0 & 0xffffu) | (d1 << 16));
        uint4 lw = make_uint4((a0 >> 16) | (a1 & 0xffff0000u), (b0 >> 16) | (b1 & 0xffff0000u),
                              (c0 >> 16) | (c1 & 0xffff0000u), (d0 >> 16) | (d1 & 0xffff0000u));
        int d = (b << 10) | ((kc * 16) ^ ((b & 7) << 4));
        *(uint4*)((char*)Hhi + d) = hw;
        *(uint4*)((char*)Hlo + d) = lw;
      }
    }
    __syncthreads();

    // ---- issue gi loads early; latency hides under the MFMA phase
    const float* gi_t = dec ? (gid + (size_t)(t - NS) * NB * 3 * NH)
                            : (gie + (size_t)t * NB * 3 * NH);
    const float* gp = gi_t + (size_t)gb * 3 * NH;
    float gr = gp[jg], gz = gp[NH + jg], gn = gp[2 * NH + jg];

    // ---- gh = W_slice(24x512) . h(32x512)^T via compensated bf16 MFMA
    f32x4 acc = {0.f, 0.f, 0.f, 0.f};
    #pragma unroll 4
    for (int kk = 0; kk < 16; ++kk){
      const int bc = kk * 64 + ((lane >> 4) << 4);
      const int ra = mt * 16 + (lane & 15);     // rows 24..31 read harmless garbage (in-bounds LDS)
      const int rb = nt * 16 + (lane & 15);
      bf16x8 ah = *(const bf16x8*)((char*)Whi + ((ra << 10) | (bc ^ ((ra & 7) << 4))));
      bf16x8 al = *(const bf16x8*)((char*)Wlo + ((ra << 10) | (bc ^ ((ra & 7) << 4))));
      bf16x8 bh = *(const bf16x8*)((char*)Hhi + ((rb << 10) | (bc ^ ((rb & 7) << 4))));
      bf16x8 bl = *(const bf16x8*)((char*)Hlo + ((rb << 10) | (bc ^ ((rb & 7) << 4))));
      acc = __builtin_amdgcn_mfma_f32_16x16x32_bf16(ah, bh, acc, 0, 0, 0);
      acc = __builtin_amdgcn_mfma_f32_16x16x32_bf16(al, bh, acc, 0, 0, 0);
      acc = __builtin_amdgcn_mfma_f32_16x16x32_bf16(ah, bl, acc, 0, 0, 0);
    }
    {
      int col = nt * 16 + (lane & 15);
      #pragma unroll
      for (int r = 0; r < 4; ++r){
        int row = mt * 16 + ((lane >> 4) << 2) + r;
        if (row < GR) GH[row * NB + col] = acc[r];
      }
    }
    __syncthreads();

    // ---- gate math: one (jj, b) per thread; publish h(t+1) via agent atomic (MALL)
    {
      float ghr = GH[(0 * HU + gjj) * NB + gb] + (dec ? bdR : beR);
      float ghz = GH[(1 * HU + gjj) * NB + gb] + (dec ? bdZ : beZ);
      float ghn = GH[(2 * HU + gjj) * NB + gb] + (dec ? bdN : beN);
      float r = 1.f / (1.f + expf(-(gr + ghr)));
      float z = 1.f / (1.f + expf(-(gz + ghz)));
      float n = tanhf(gn + r * ghn);
      int bc2 = (jg * 2) ^ ((gb & 7) << 4);
      float hp = bf2f(*(const u16*)((char*)Hhi + ((gb << 10) | bc2)))
               + bf2f(*(const u16*)((char*)Hlo + ((gb << 10) | bc2)));
      float hnew = (1.f - z) * n + z * hp;
      u16 hi = f2bf(hnew);
      u16 lo = f2bf(hnew - bf2f(hi));
      __hip_atomic_store(&Hpk[((size_t)((t + 1) & 1) * NB + gb) * NH + jg],
                         (unsigned)hi | ((unsigned)lo << 16),
                         __ATOMIC_RELAXED, __HIP_MEMORY_SCOPE_AGENT);
      if (dec) Hall[((size_t)(t - NS) * NB + gb) * NH + jg] = hi;
    }

    if (t == TSTEPS - 1) break;

    // ---- publish flag: syncthreads drains each wave's vmcnt (atomics acked at MALL) first
    __syncthreads();
    if (tid == 0)
      __hip_atomic_store(&flags[blockIdx.x * 4], (unsigned)(t + 1),
                         __ATOMIC_RELAXED, __HIP_MEMORY_SCOPE_AGENT);
  }
}

// ---------------------------------------------------------------- launcher
extern "C" void kernel_launch(void* const* d_in, const int* in_sizes, int n_in,
                              void* d_out, int out_size, void* d_ws, size_t ws_size,
                              hipStream_t stream)
{
  const int*   src      = (const int*)  d_in[0];
  const int*   trg      = (const int*)  d_in[1];
  const float* emb_enc  = (const float*)d_in[2];
  const float* W_ih_enc = (const float*)d_in[3];
  const float* W_hh_enc = (const float*)d_in[4];
  const float* b_ih_enc = (const float*)d_in[5];
  const float* b_hh_enc = (const float*)d_in[6];
  const float* emb_dec  = (const float*)d_in[7];
  const float* W_ih_dec = (const float*)d_in[8];
  const float* W_hh_dec = (const float*)d_in[9];
  const float* b_ih_dec = (const float*)d_in[10];
  const float* b_hh_dec = (const float*)d_in[11];
  const float* fc_W     = (const float*)d_in[12];
  const float* fc_b     = (const float*)d_in[13];
  float* out = (float*)d_out;

  char* ws = (char*)d_ws;
  size_t o = 0;
  auto alloc = [&](size_t bytes){ size_t r = o; o += (bytes + 255) & ~(size_t)255; return r; };
  u16*   xenc  = (u16*)(ws + alloc((size_t)2048 * NE * 2));
  u16*   xdec  = (u16*)(ws + alloc((size_t)2048 * NE * 2));   // 2016 used + 32 pad
  u16*   wihe  = (u16*)(ws + alloc((size_t)3 * NH * NE * 2));
  u16*   wihd  = (u16*)(ws + alloc((size_t)3 * NH * NE * 2));
  u16*   fcWbf = (u16*)(ws + alloc((size_t)NV * NH * 2));
  u16*   whiE  = (u16*)(ws + alloc((size_t)3 * NH * NH * 2));
  u16*   wloE  = (u16*)(ws + alloc((size_t)3 * NH * NH * 2));
  u16*   whiD  = (u16*)(ws + alloc((size_t)3 * NH * NH * 2));
  u16*   wloD  = (u16*)(ws + alloc((size_t)3 * NH * NH * 2));
  float* gie   = (float*)(ws + alloc((size_t)2048 * 3 * NH * 4));
  float* gid   = (float*)(ws + alloc((size_t)2048 * 3 * NH * 4));
  unsigned* Hpk   = (unsigned*)(ws + alloc((size_t)2 * NB * NH * 4));  // packed h slots
  unsigned* flags = (unsigned*)(ws + alloc(4096));
  u16*   Hall  = (u16*)(ws + alloc((size_t)2048 * NH * 2));   // 2016 used + 32 pad

  zero_init<<<256, 256, 0, stream>>>(out, xdec + (size_t)2016 * NE, Hall + (size_t)2016 * NH, Hpk, flags);
  cvt_f32_bf16<<<384, 256, 0, stream>>>(W_ih_enc, wihe, 3*NH*NE/4);
  cvt_f32_bf16<<<384, 256, 0, stream>>>(W_ih_dec, wihd, 3*NH*NE/4);
  cvt_f32_bf16<<<2048, 256, 0, stream>>>(fc_W, fcWbf, NV*NH/4);
  cvt_hilo<<<1024, 256, 0, stream>>>(W_hh_enc, whiE, wloE, 3*NH*NH);
  cvt_hilo<<<1024, 256, 0, stream>>>(W_hh_dec, whiD, wloD, 3*NH*NH);
  embed_k<<<(NS*NB*64 + 255)/256, 256, 0, stream>>>(src, NS, NS, emb_enc, xenc);
  embed_k<<<((NT-1)*NB*64 + 255)/256, 256, 0, stream>>>(trg, NT, NT-1, emb_dec, xdec);

  // gi = x @ W_ih^T + b_ih   (M=2048, N=1536, K=256) -> grid 12*16 = 192
  gemm_bt<NE, false><<<192, 256, 0, stream>>>(xenc, wihe, b_ih_enc, gie, 2048, 3*NH);
  gemm_bt<NE, false><<<192, 256, 0, stream>>>(xdec, wihd, b_ih_dec, gid, 2048, 3*NH);

  // persistent recurrence (MALL-coherent sync, no fences, no RMW barrier)
  constexpr int SMEM_BYTES = (GR * NH + NB * NH) * 2 /*hi+lo*/ * 2 /*bytes*/ + GR * NB * 4; // 117760
  static_assert(SMEM_BYTES <= 160 * 1024, "LDS over 160 KiB");
  static_assert(SMEM_BYTES == 117760, "unexpected LDS size");
  (void)hipFuncSetAttribute(reinterpret_cast<const void*>(&gru_rec),
                            hipFuncAttributeMaxDynamicSharedMemorySize, SMEM_BYTES);
  gru_rec<<<RG, 256, SMEM_BYTES, stream>>>(whiE, wloE, whiD, wloD, b_hh_enc, b_hh_dec,
                                           gie, gid, Hpk, flags, Hall);

  // logits = h2 @ fc_W^T + fc_b  (M=2048 pad, N=32000, K=512) -> grid 250*16 = 4000
  gemm_bt<NH, true><<<4000, 256, 0, stream>>>(Hall, fcWbf, fc_b, out, 2016, 0);
}